// Round 5
// baseline (205.843 us; speedup 1.0000x reference)
//
#include <hip/hip_runtime.h>
#include <hip/hip_bf16.h>

// Problem constants: N tokens, D d_model, E experts, H hidden, K top-k
#define NTOK 4096
#define DM   512
#define NE   32
#define HD   128
#define TK   4
#define RB   512    // router blocks (8 tokens each)
#define SLOTW 32    // tok_list slots per (expert, router-block): 8 tok * K=4
#define MGRID 512   // mlp grid: 2 blocks/CU, co-resident (46KB LDS, bounds(256,2))

typedef unsigned short u16;
typedef unsigned int   u32;
typedef u16   u16x4 __attribute__((ext_vector_type(4)));
typedef u16   u16x8 __attribute__((ext_vector_type(8)));
typedef short short8 __attribute__((ext_vector_type(8)));
typedef float f32x4 __attribute__((ext_vector_type(4)));
typedef int   int2v __attribute__((ext_vector_type(2)));

__device__ __forceinline__ u16 f2bf(float f) {
    union { float f; u32 u; } v; v.f = f;
    return (u16)((v.u + 0x7FFFu + ((v.u >> 16) & 1u)) >> 16);   // RNE
}
__device__ __forceinline__ float bf2f(u16 h) {
    union { u32 u; float f; } v; v.u = ((u32)h) << 16; return v.f;
}

// Device-scope grid barrier (mechanics validated in round-2's passing run).
__device__ __forceinline__ void grid_sync(u32* bar, u32 target) {
    __syncthreads();
    if (threadIdx.x == 0) {
        __hip_atomic_fetch_add(bar, 1u, __ATOMIC_ACQ_REL, __HIP_MEMORY_SCOPE_AGENT);
        while (__hip_atomic_load(bar, __ATOMIC_ACQUIRE, __HIP_MEMORY_SCOPE_AGENT) < target)
            __builtin_amdgcn_s_sleep(2);
    }
    __syncthreads();
}

// ---------------- fused prep ----------------
// blocks [0,512):      router, 8 tokens/block (verified round-2 fp64 math);
//                      deterministic per-(block,expert) slots, no atomics, no memset.
// blocks [512,1536):   weight swizzle fp32 -> bf16 fragment-major (verbatim).
__global__ __launch_bounds__(256) void prep_kernel(const float* __restrict__ x,
                                                   const float* __restrict__ sel,
                                                   const float* __restrict__ w1,
                                                   const float* __restrict__ w2,
                                                   int* __restrict__ blk_cnt,
                                                   u32* __restrict__ bar,
                                                   int* __restrict__ tok_list,
                                                   float* __restrict__ gate_list,
                                                   u16* __restrict__ xbf,
                                                   u16* __restrict__ wf1,
                                                   u16* __restrict__ wf2) {
    __shared__ __align__(16) float  xs[8][520];     // 16.6 KB
    __shared__ double sc[8][33];                    // 2.1 KB
    __shared__ int    pk_e[32];
    __shared__ float  pk_g[32];
    int tid = threadIdx.x;
    int wv = tid >> 6, lane = tid & 63;

    if (blockIdx.x == 0 && tid == 0) *bar = 0;      // re-init barrier each replay

    if (blockIdx.x >= RB) {
        // ---- weight swizzle: 2 fragments per wave ----
        int m = lane & 15, q = lane >> 4;
        int f0 = ((blockIdx.x - RB) * 4 + wv) * 2;
        const float* in[2]; u16* outp[2]; int Nd[2];
#pragma unroll
        for (int u = 0; u < 2; ++u) {
            int w = f0 + u;
            if (w < 4096) {
                int e = w >> 7, rem = w & 127, ks = rem >> 3, nt = rem & 7;
                in[u] = w1 + (size_t)e * DM * HD + (size_t)(32 * ks + q * 8) * HD + 16 * nt + m;
                Nd[u] = HD;
                outp[u] = wf1 + (size_t)w * 512 + lane * 8;
            } else {
                int wl = w - 4096, e = wl >> 7, rem = wl & 127, ks = rem >> 5, nt = rem & 31;
                in[u] = w2 + (size_t)e * HD * DM + (size_t)(32 * ks + q * 8) * DM + 16 * nt + m;
                Nd[u] = DM;
                outp[u] = wf2 + (size_t)wl * 512 + lane * 8;
            }
        }
        float v[2][8];
#pragma unroll
        for (int u = 0; u < 2; ++u)
#pragma unroll
            for (int j = 0; j < 8; ++j) v[u][j] = in[u][(size_t)j * Nd[u]];
#pragma unroll
        for (int u = 0; u < 2; ++u) {
            u16x8 h;
#pragma unroll
            for (int j = 0; j < 8; ++j) h[j] = f2bf(v[u][j]);
            *(u16x8*)outp[u] = h;
        }
        return;
    }

    // ---- router: 8 tokens/block (round-2 verified math) ----
    int bl = blockIdx.x;
    int tb = bl * 8;
#pragma unroll
    for (int rep = 0; rep < 4; ++rep) {
        int idx = (rep * 256 + tid) * 4;            // element in 8x512 tile
        int row = idx >> 9, col = idx & 511;
        f32x4 v = *(const f32x4*)(x + (size_t)(tb + row) * DM + col);
        *(f32x4*)&xs[row][col] = v;
        u16x4 h;
#pragma unroll
        for (int j = 0; j < 4; ++j) h[j] = f2bf(v[j]);
        *(u16x4*)(xbf + (size_t)(tb + row) * DM + col) = h;
    }
    __syncthreads();

    // thread: tok = tid&7, e = tid>>3; full 512-long fp64 dot, 4 chains,
    // combined (a0+a1)+(a2+a3) — summation order identical to verified router.
    {
        int tok = tid & 7, e = tid >> 3;
        const float* sp = sel + (size_t)e * DM;
        const float* xp = xs[tok];
        double pa = 0.0, pb = 0.0, pc = 0.0, pd = 0.0;
#pragma unroll 4
        for (int j = 0; j < 512; j += 16) {
            f32x4 x0 = *(const f32x4*)(xp + j);
            f32x4 x1 = *(const f32x4*)(xp + j + 4);
            f32x4 x2 = *(const f32x4*)(xp + j + 8);
            f32x4 x3 = *(const f32x4*)(xp + j + 12);
            f32x4 s0 = *(const f32x4*)(sp + j);
            f32x4 s1 = *(const f32x4*)(sp + j + 4);
            f32x4 s2 = *(const f32x4*)(sp + j + 8);
            f32x4 s3 = *(const f32x4*)(sp + j + 12);
#pragma unroll
            for (int k = 0; k < 4; ++k) {
                pa = fma((double)x0[k], (double)s0[k], pa);
                pb = fma((double)x1[k], (double)s1[k], pb);
                pc = fma((double)x2[k], (double)s2[k], pc);
                pd = fma((double)x3[k], (double)s3[k], pd);
            }
        }
        sc[tok][e] = (pa + pb) + (pc + pd);
    }
    __syncthreads();

    // top-k per token -> LDS pick lists
    if (tid < 8) {
        unsigned mask = 0;
        for (int k = 0; k < TK; ++k) {
            double best = -1e300; int be = 0;
            for (int ee = 0; ee < NE; ++ee) {
                double v = sc[tid][ee];
                if (!((mask >> ee) & 1u) && v > best) { best = v; be = ee; }
            }
            mask |= 1u << be;
            pk_e[tid * 4 + k] = be;
            pk_g[tid * 4 + k] = 1.0f / (1.0f + __expf(-(float)best));
        }
    }
    __syncthreads();

    // deterministic append: expert tid owns tok_list[(tid*RB+bl)*SLOTW ..]
    if (tid < NE) {
        int e2 = tid, cnt = 0;
        int base = (e2 * RB + bl) * SLOTW;
#pragma unroll
        for (int i = 0; i < 32; ++i) {
            if (pk_e[i] == e2) {
                tok_list[base + cnt]  = ((i & 3) << 16) | (tb + (i >> 2));
                gate_list[base + cnt] = pk_g[i];
                ++cnt;
            }
        }
        blk_cnt[e2 * RB + bl] = cnt;                // written for EVERY (e,bl)
    }
}

// ---------------- fused expert MLP + combine ----------------
// Grid MGRID=512 (8 XCD groups x 64), internal tile loop; after all tiles,
// grid-wide barrier, then combine distributed over the same blocks.
__global__ __launch_bounds__(256, 2) void moe_mlp_kernel(const u16* __restrict__ xbf,
                                                         const u16* __restrict__ wf1,
                                                         const u16* __restrict__ wf2,
                                                         const int* __restrict__ blk_cnt,
                                                         const int* __restrict__ tok_list,
                                                         const float* __restrict__ gate_list,
                                                         u32* __restrict__ bar,
                                                         u16* __restrict__ part,
                                                         float* __restrict__ out,
                                                         int use_part) {
    __shared__ int   s_tot[4];
    __shared__ int   s_red[4][4];                   // [wave][slot]
    __shared__ int   s_pref[RB + 1];                // 2.1 KB
    __shared__ int   s_ent[32];
    __shared__ float s_gate[32];
    __shared__ __align__(16) u16 Hm[32][136];       // 272B stride
    __shared__ __align__(16) u16 Ct[32][520];       // 1040B stride

    int tid = threadIdx.x;
    int wv = tid >> 6, lane = tid & 63;
    int xcd = blockIdx.x & 7, idx0 = blockIdx.x >> 3;   // 64 blocks per group

    // ---- per-expert totals for this group's 4 experts ----
#pragma unroll
    for (int j = 0; j < 4; ++j) {
        int2v v = *(const int2v*)&blk_cnt[(size_t)(xcd + 8 * j) * RB + tid * 2];
        int s = v[0] + v[1];
#pragma unroll
        for (int off = 32; off >= 1; off >>= 1) s += __shfl_down(s, off);
        if (lane == 0) s_red[wv][j] = s;
    }
    __syncthreads();
    if (tid < 4) s_tot[tid] = s_red[0][tid] + s_red[1][tid] + s_red[2][tid] + s_red[3][tid];
    __syncthreads();

    int c0 = s_tot[0], c1 = s_tot[1], c2 = s_tot[2], c3 = s_tot[3];
    int n0 = (c0 + 31) >> 5, n1 = (c1 + 31) >> 5, n2 = (c2 + 31) >> 5, n3 = (c3 + 31) >> 5;
    int tot = n0 + n1 + n2 + n3;

    int m = lane & 15, q = lane >> 4;
    int r = wv >> 1, c = wv & 1;                    // GEMM1: rows 16r..+16, cols 64c..+64
    int e_last = -1;

    for (int idx = idx0; idx < tot; idx += 64) {
        int e2, t2, cc;
        if (idx < n0)                { e2 = xcd;      t2 = idx;                cc = c0; }
        else if (idx < n0 + n1)      { e2 = xcd + 8;  t2 = idx - n0;           cc = c1; }
        else if (idx < n0 + n1 + n2) { e2 = xcd + 16; t2 = idx - n0 - n1;      cc = c2; }
        else                         { e2 = xcd + 24; t2 = idx - n0 - n1 - n2; cc = c3; }
        int rows = cc - t2 * 32; if (rows > 32) rows = 32;

        __syncthreads();                            // prev iter's Ct/s_ent readers done

        if (e2 != e_last) {
            // exclusive prefix scan of blk_cnt[e2][0..RB) into s_pref
            int2v v = *(const int2v*)&blk_cnt[(size_t)e2 * RB + tid * 2];
            int lsum = v[0] + v[1];
            int incl = lsum;
#pragma unroll
            for (int off = 1; off < 64; off <<= 1) {
                int t3 = __shfl_up(incl, off);
                if (lane >= off) incl += t3;
            }
            if (lane == 63) s_red[0][wv] = incl;
            __syncthreads();
            int woff = 0;
#pragma unroll
            for (int w2 = 0; w2 < 4; ++w2) if (w2 < wv) woff += s_red[0][w2];
            int excl = woff + incl - lsum;
            s_pref[tid * 2 + 0] = excl;
            s_pref[tid * 2 + 1] = excl + v[0];
            if (tid == 255) s_pref[RB] = excl + lsum;
            e_last = e2;
            __syncthreads();
        }

        // gather this tile's 32 entries via binary search on s_pref
        if (tid < 32) {
            int row = t2 * 32 + tid;
            bool val = tid < rows;
            int rr = val ? row : 0;
            int lo = 0, hi = RB;
            while (hi - lo > 1) { int mid = (lo + hi) >> 1; if (s_pref[mid] <= rr) lo = mid; else hi = mid; }
            int sub = rr - s_pref[lo];
            s_ent[tid]  = tok_list[((size_t)e2 * RB + lo) * SLOTW + sub];
            s_gate[tid] = val ? gate_list[((size_t)e2 * RB + lo) * SLOTW + sub] : 0.0f;
        }
        __syncthreads();

        const u16* w1f = wf1 + (size_t)e2 * (128 * 512);
        const u16* w2f = wf2 + (size_t)e2 * (128 * 512);
        const u16* a0 = xbf + (size_t)(s_ent[16 * r + m] & 0xFFFF) * DM + q * 8;

        // GEMM1: k-steps in pairs, double-buffered
        short8 ab[2][2];
        short8 bb[2][2][4];
#pragma unroll
        for (int kk = 0; kk < 2; ++kk) {
            ab[0][kk] = *(const short8*)(a0 + 32 * kk);
            const u16* bp = w1f + (size_t)kk * 4096 + (size_t)(4 * c) * 512 + lane * 8;
#pragma unroll
            for (int n = 0; n < 4; ++n) bb[0][kk][n] = *(const short8*)(bp + n * 512);
        }
        f32x4 acc[4];
#pragma unroll
        for (int n = 0; n < 4; ++n) acc[n] = (f32x4){0.f, 0.f, 0.f, 0.f};

#pragma unroll
        for (int kp = 0; kp < 8; ++kp) {
            int cur = kp & 1, nxt = cur ^ 1;
            if (kp < 7) {
                int ks0 = 2 * (kp + 1);
#pragma unroll
                for (int kk = 0; kk < 2; ++kk) {
                    ab[nxt][kk] = *(const short8*)(a0 + 32 * (ks0 + kk));
                    const u16* bp = w1f + (size_t)(ks0 + kk) * 4096 + (size_t)(4 * c) * 512 + lane * 8;
#pragma unroll
                    for (int n = 0; n < 4; ++n) bb[nxt][kk][n] = *(const short8*)(bp + n * 512);
                }
            }
#pragma unroll
            for (int kk = 0; kk < 2; ++kk)
#pragma unroll
                for (int n = 0; n < 4; ++n)
                    acc[n] = __builtin_amdgcn_mfma_f32_16x16x32_bf16(ab[cur][kk],
                                                                     bb[cur][kk][n],
                                                                     acc[n], 0, 0, 0);
        }

        // relu * gate -> Hm
        {
            int rb = 16 * r + q * 4;
#pragma unroll
            for (int n = 0; n < 4; ++n)
#pragma unroll
                for (int rr2 = 0; rr2 < 4; ++rr2)
                    Hm[rb + rr2][64 * c + 16 * n + m] =
                        f2bf(fmaxf(acc[n][rr2], 0.f) * s_gate[rb + rr2]);
        }

        // GEMM2: wave owns cols [128*wv, +128); w2 frags double-buffered per k-slice
        short8 cb[2][8];
        {
            const u16* bp = w2f + (size_t)(wv * 8) * 512 + lane * 8;
#pragma unroll
            for (int n = 0; n < 8; ++n) cb[0][n] = *(const short8*)(bp + n * 512);
        }
        __syncthreads();                            // Hm ready

        f32x4 acc2[2][8];
#pragma unroll
        for (int i = 0; i < 2; ++i)
#pragma unroll
            for (int n = 0; n < 8; ++n) acc2[i][n] = (f32x4){0.f, 0.f, 0.f, 0.f};
#pragma unroll
        for (int ks = 0; ks < 4; ++ks) {
            int cur = ks & 1, nxt = cur ^ 1;
            if (ks < 3) {
                const u16* bp = w2f + (size_t)((ks + 1) * 32 + wv * 8) * 512 + lane * 8;
#pragma unroll
                for (int n = 0; n < 8; ++n) cb[nxt][n] = *(const short8*)(bp + n * 512);
            }
            short8 h0 = *(const short8*)&Hm[m][32 * ks + q * 8];
            short8 h1 = *(const short8*)&Hm[16 + m][32 * ks + q * 8];
#pragma unroll
            for (int n = 0; n < 8; ++n) {
                acc2[0][n] = __builtin_amdgcn_mfma_f32_16x16x32_bf16(h0, cb[cur][n], acc2[0][n], 0, 0, 0);
                acc2[1][n] = __builtin_amdgcn_mfma_f32_16x16x32_bf16(h1, cb[cur][n], acc2[1][n], 0, 0, 0);
            }
        }

        // C-layout -> LDS transpose (each wave writes its 128-col stripe)
#pragma unroll
        for (int i = 0; i < 2; ++i) {
            int rb = 16 * i + q * 4;
#pragma unroll
            for (int n = 0; n < 8; ++n)
#pragma unroll
                for (int rr2 = 0; rr2 < 4; ++rr2)
                    Ct[rb + rr2][128 * wv + 16 * n + m] = f2bf(acc2[i][n][rr2]);
        }
        __syncthreads();                            // Ct complete
        // contiguous row stores
#pragma unroll
        for (int rep = 0; rep < 8; ++rep) {
            int rl = rep * 4 + wv;                  // 0..31
            u16x8 v = *(const u16x8*)&Ct[rl][lane * 8];
            if (rl < rows) {
                int en = s_ent[rl];
                int tk = en & 0xFFFF, sl2 = en >> 16;
                if (use_part) {
                    *(u16x8*)(part + ((size_t)sl2 * NTOK + tk) * DM + lane * 8) = v;
                } else {
                    float* op = out + (size_t)tk * DM + lane * 8;
#pragma unroll
                    for (int j = 0; j < 8; ++j) atomicAdd(&op[j], bf2f(v[j]));
                }
            }
        }
        __syncthreads();                            // Ct reusable next iter
    }

    if (!use_part) return;                          // fallback: no barrier needed

    grid_sync(bar, MGRID);                          // all part slots written

    // ---- combine: out[t][c] = sum_k part[k][t][c], distributed over MGRID ----
#pragma unroll
    for (int rep = 0; rep < 2; ++rep) {
        size_t off = (((size_t)blockIdx.x + (size_t)rep * MGRID) * 256 + tid) * 8;
        float s[8] = {0, 0, 0, 0, 0, 0, 0, 0};
#pragma unroll
        for (int k = 0; k < TK; ++k) {
            u16x8 p = *(const u16x8*)(part + (size_t)k * NTOK * DM + off);
#pragma unroll
            for (int j = 0; j < 8; ++j) s[j] += bf2f(p[j]);
        }
        *(f32x4*)(out + off)     = (f32x4){s[0], s[1], s[2], s[3]};
        *(f32x4*)(out + off + 4) = (f32x4){s[4], s[5], s[6], s[7]};
    }
}

extern "C" void kernel_launch(void* const* d_in, const int* in_sizes, int n_in,
                              void* d_out, int out_size, void* d_ws, size_t ws_size,
                              hipStream_t stream) {
    (void)in_sizes; (void)n_in; (void)out_size;
    const float* x   = (const float*)d_in[0];   // [N, D]
    const float* sel = (const float*)d_in[1];   // [E, D]
    const float* w1  = (const float*)d_in[2];   // [E, D, H]
    const float* w2  = (const float*)d_in[3];   // [E, H, D]
    float* out = (float*)d_out;                 // [N, D]

    char* ws = (char*)d_ws;
    int*   blk_cnt   = (int*)(ws);                                   // 64 KB
    u32*   bar       = (u32*)(ws + (size_t)NE * RB * 4);             // 256 B
    int*   tok_list  = (int*)(ws + (size_t)NE * RB * 4 + 256);       // 2 MB
    float* gate_list = (float*)((char*)tok_list + (size_t)NE * RB * SLOTW * 4); // 2 MB
    u16*   xbf  = (u16*)((char*)gate_list + (size_t)NE * RB * SLOTW * 4);       // 4 MB
    u16*   wf1  = xbf + (size_t)NTOK * DM;                           // 4 MB
    u16*   wf2  = wf1 + (size_t)NE * HD * DM;                        // 4 MB
    u16*   part = wf2 + (size_t)NE * HD * DM;                        // 16.8 MB

    size_t need = (size_t)NE * RB * 4 + 256 + 2 * (size_t)NE * RB * SLOTW * 4
                + (size_t)NTOK * DM * 2 + 2 * (size_t)NE * HD * DM * 2
                + (size_t)TK * NTOK * DM * 2;
    int use_part = (ws_size >= need) ? 1 : 0;

    if (!use_part)
        hipMemsetAsync(d_out, 0, (size_t)NTOK * DM * sizeof(float), stream);

    // blocks [0,512) router (8 tok/block); [512,1536) swizzle. No memset nodes
    // on the main path (blk_cnt written unconditionally; bar zeroed by block 0).
    prep_kernel<<<1536, 256, 0, stream>>>(x, sel, w1, w2, blk_cnt, bar, tok_list,
                                          gate_list, xbf, wf1, wf2);
    // 8 XCD groups x 64 blocks, tile loop + grid barrier + fused combine
    moe_mlp_kernel<<<MGRID, 256, 0, stream>>>(xbf, wf1, wf2, blk_cnt, tok_list,
                                              gate_list, bar, part, out, use_part);
}

// Round 6
// 141.430 us; speedup vs baseline: 1.4554x; 1.4554x over previous
//
#include <hip/hip_runtime.h>
#include <hip/hip_bf16.h>

// Problem constants: N tokens, D d_model, E experts, H hidden, K top-k
#define NTOK 4096
#define DM   512
#define NE   32
#define HD   128
#define TK   4
#define RB   512    // router blocks (8 tokens each)
#define SLOTW 32    // tok_list slots per (expert, router-block): 8 tok * K=4

typedef unsigned short u16;
typedef unsigned int   u32;
typedef u16   u16x4 __attribute__((ext_vector_type(4)));
typedef u16   u16x8 __attribute__((ext_vector_type(8)));
typedef short short8 __attribute__((ext_vector_type(8)));
typedef float f32x4 __attribute__((ext_vector_type(4)));
typedef int   int2v __attribute__((ext_vector_type(2)));

__device__ __forceinline__ u16 f2bf(float f) {
    union { float f; u32 u; } v; v.f = f;
    return (u16)((v.u + 0x7FFFu + ((v.u >> 16) & 1u)) >> 16);   // RNE
}
__device__ __forceinline__ float bf2f(u16 h) {
    union { u32 u; float f; } v; v.u = ((u32)h) << 16; return v.f;
}

// ---------------- fused prep ----------------
// blocks [0,512):      router, 8 tokens/block (verified R5 fp64 math);
//                      deterministic per-(block,expert) slots, no atomics, no memset;
//                      also zeroes done[] (8 tokens/block).
// blocks [512,1536):   weight swizzle fp32 -> bf16 fragment-major (verbatim).
__global__ __launch_bounds__(256) void prep_kernel(const float* __restrict__ x,
                                                   const float* __restrict__ sel,
                                                   const float* __restrict__ w1,
                                                   const float* __restrict__ w2,
                                                   int* __restrict__ blk_cnt,
                                                   u32* __restrict__ done,
                                                   int* __restrict__ tok_list,
                                                   float* __restrict__ gate_list,
                                                   u16* __restrict__ xbf,
                                                   u16* __restrict__ wf1,
                                                   u16* __restrict__ wf2) {
    __shared__ __align__(16) float  xs[8][520];     // 16.6 KB
    __shared__ double sc[8][33];                    // 2.1 KB
    __shared__ int    pk_e[32];
    __shared__ float  pk_g[32];
    int tid = threadIdx.x;
    int wv = tid >> 6, lane = tid & 63;

    if (blockIdx.x >= RB) {
        // ---- weight swizzle: 2 fragments per wave ----
        int m = lane & 15, q = lane >> 4;
        int f0 = ((blockIdx.x - RB) * 4 + wv) * 2;
        const float* in[2]; u16* outp[2]; int Nd[2];
#pragma unroll
        for (int u = 0; u < 2; ++u) {
            int w = f0 + u;
            if (w < 4096) {
                int e = w >> 7, rem = w & 127, ks = rem >> 3, nt = rem & 7;
                in[u] = w1 + (size_t)e * DM * HD + (size_t)(32 * ks + q * 8) * HD + 16 * nt + m;
                Nd[u] = HD;
                outp[u] = wf1 + (size_t)w * 512 + lane * 8;
            } else {
                int wl = w - 4096, e = wl >> 7, rem = wl & 127, ks = rem >> 5, nt = rem & 31;
                in[u] = w2 + (size_t)e * HD * DM + (size_t)(32 * ks + q * 8) * DM + 16 * nt + m;
                Nd[u] = DM;
                outp[u] = wf2 + (size_t)wl * 512 + lane * 8;
            }
        }
        float v[2][8];
#pragma unroll
        for (int u = 0; u < 2; ++u)
#pragma unroll
            for (int j = 0; j < 8; ++j) v[u][j] = in[u][(size_t)j * Nd[u]];
#pragma unroll
        for (int u = 0; u < 2; ++u) {
            u16x8 h;
#pragma unroll
            for (int j = 0; j < 8; ++j) h[j] = f2bf(v[u][j]);
            *(u16x8*)outp[u] = h;
        }
        return;
    }

    // ---- router: 8 tokens/block ----
    int bl = blockIdx.x;
    int tb = bl * 8;
    if (tid < 8) done[tb + tid] = 0u;               // zero completion counters
#pragma unroll
    for (int rep = 0; rep < 4; ++rep) {
        int idx = (rep * 256 + tid) * 4;            // element in 8x512 tile
        int row = idx >> 9, col = idx & 511;
        f32x4 v = *(const f32x4*)(x + (size_t)(tb + row) * DM + col);
        *(f32x4*)&xs[row][col] = v;
        u16x4 h;
#pragma unroll
        for (int j = 0; j < 4; ++j) h[j] = f2bf(v[j]);
        *(u16x4*)(xbf + (size_t)(tb + row) * DM + col) = h;
    }
    __syncthreads();

    // thread: tok = tid&7, e = tid>>3; full 512-long fp64 dot, 4 chains,
    // combined (pa+pb)+(pc+pd) — summation order identical to verified router.
    {
        int tok = tid & 7, e = tid >> 3;
        const float* sp = sel + (size_t)e * DM;
        const float* xp = xs[tok];
        double pa = 0.0, pb = 0.0, pc = 0.0, pd = 0.0;
#pragma unroll 4
        for (int j = 0; j < 512; j += 16) {
            f32x4 x0 = *(const f32x4*)(xp + j);
            f32x4 x1 = *(const f32x4*)(xp + j + 4);
            f32x4 x2 = *(const f32x4*)(xp + j + 8);
            f32x4 x3 = *(const f32x4*)(xp + j + 12);
            f32x4 s0 = *(const f32x4*)(sp + j);
            f32x4 s1 = *(const f32x4*)(sp + j + 4);
            f32x4 s2 = *(const f32x4*)(sp + j + 8);
            f32x4 s3 = *(const f32x4*)(sp + j + 12);
#pragma unroll
            for (int k = 0; k < 4; ++k) {
                pa = fma((double)x0[k], (double)s0[k], pa);
                pb = fma((double)x1[k], (double)s1[k], pb);
                pc = fma((double)x2[k], (double)s2[k], pc);
                pd = fma((double)x3[k], (double)s3[k], pd);
            }
        }
        sc[tok][e] = (pa + pb) + (pc + pd);
    }
    __syncthreads();

    // top-k per token -> LDS pick lists
    if (tid < 8) {
        unsigned mask = 0;
        for (int k = 0; k < TK; ++k) {
            double best = -1e300; int be = 0;
            for (int ee = 0; ee < NE; ++ee) {
                double v = sc[tid][ee];
                if (!((mask >> ee) & 1u) && v > best) { best = v; be = ee; }
            }
            mask |= 1u << be;
            pk_e[tid * 4 + k] = be;
            pk_g[tid * 4 + k] = 1.0f / (1.0f + __expf(-(float)best));
        }
    }
    __syncthreads();

    // deterministic append: expert tid owns tok_list[(tid*RB+bl)*SLOTW ..]
    if (tid < NE) {
        int e2 = tid, cnt = 0;
        int base = (e2 * RB + bl) * SLOTW;
#pragma unroll
        for (int i = 0; i < 32; ++i) {
            if (pk_e[i] == e2) {
                tok_list[base + cnt]  = ((i & 3) << 16) | (tb + (i >> 2));
                gate_list[base + cnt] = pk_g[i];
                ++cnt;
            }
        }
        blk_cnt[e2 * RB + bl] = cnt;                // written for EVERY (e,bl)
    }
}

// ---------------- fused expert MLP + completion-counter combine ----------------
// Grid 1024 (8 XCD groups x 128), internal tile loop. After each tile's part-row
// stores, threads ACQ_REL-increment done[token]; the increment seeing old==3 wins
// the token and the block combines its 4 part rows into out (L2-hot). No spin,
// no extra dispatch. LDS 27.9 KB (Ct 16 rows, 2-pass epilogue) -> ~4 blocks/CU.
__global__ __launch_bounds__(256, 2) void moe_mlp_kernel(const u16* __restrict__ xbf,
                                                         const u16* __restrict__ wf1,
                                                         const u16* __restrict__ wf2,
                                                         const int* __restrict__ blk_cnt,
                                                         const int* __restrict__ tok_list,
                                                         const float* __restrict__ gate_list,
                                                         u32* __restrict__ done,
                                                         u16* __restrict__ part,
                                                         float* __restrict__ out,
                                                         int use_part) {
    __shared__ int   s_tot[4];
    __shared__ int   s_red[4][4];                   // [wave][slot]
    __shared__ int   s_pref[RB + 1];                // 2.1 KB
    __shared__ int   s_ent[32];
    __shared__ float s_gate[32];
    __shared__ int   s_win[32];
    __shared__ __align__(16) u16 Hm[32][136];       // 8.7 KB
    __shared__ __align__(16) u16 Ct[16][520];       // 16.6 KB (half-height, 2 passes)

    int tid = threadIdx.x;
    int wv = tid >> 6, lane = tid & 63;
    int xcd = blockIdx.x & 7, idx0 = blockIdx.x >> 3;   // 128 blocks per group

    // ---- per-expert totals for this group's 4 experts ----
#pragma unroll
    for (int j = 0; j < 4; ++j) {
        int2v v = *(const int2v*)&blk_cnt[(size_t)(xcd + 8 * j) * RB + tid * 2];
        int s = v[0] + v[1];
#pragma unroll
        for (int off = 32; off >= 1; off >>= 1) s += __shfl_down(s, off);
        if (lane == 0) s_red[wv][j] = s;
    }
    __syncthreads();
    if (tid < 4) s_tot[tid] = s_red[0][tid] + s_red[1][tid] + s_red[2][tid] + s_red[3][tid];
    __syncthreads();

    int c0 = s_tot[0], c1 = s_tot[1], c2 = s_tot[2], c3 = s_tot[3];
    int n0 = (c0 + 31) >> 5, n1 = (c1 + 31) >> 5, n2 = (c2 + 31) >> 5, n3 = (c3 + 31) >> 5;
    int tot = n0 + n1 + n2 + n3;

    int m = lane & 15, q = lane >> 4;
    int r = wv >> 1, c = wv & 1;                    // GEMM1: rows 16r..+16, cols 64c..+64
    int e_last = -1;

    for (int idx = idx0; idx < tot; idx += 128) {
        int e2, t2, cc;
        if (idx < n0)                { e2 = xcd;      t2 = idx;                cc = c0; }
        else if (idx < n0 + n1)      { e2 = xcd + 8;  t2 = idx - n0;           cc = c1; }
        else if (idx < n0 + n1 + n2) { e2 = xcd + 16; t2 = idx - n0 - n1;      cc = c2; }
        else                         { e2 = xcd + 24; t2 = idx - n0 - n1 - n2; cc = c3; }
        int rows = cc - t2 * 32; if (rows > 32) rows = 32;

        __syncthreads();                            // prev iter's readers done

        if (e2 != e_last) {
            // exclusive prefix scan of blk_cnt[e2][0..RB) into s_pref
            int2v v = *(const int2v*)&blk_cnt[(size_t)e2 * RB + tid * 2];
            int lsum = v[0] + v[1];
            int incl = lsum;
#pragma unroll
            for (int off = 1; off < 64; off <<= 1) {
                int t3 = __shfl_up(incl, off);
                if (lane >= off) incl += t3;
            }
            if (lane == 63) s_red[0][wv] = incl;
            __syncthreads();
            int woff = 0;
#pragma unroll
            for (int w2 = 0; w2 < 4; ++w2) if (w2 < wv) woff += s_red[0][w2];
            int excl = woff + incl - lsum;
            s_pref[tid * 2 + 0] = excl;
            s_pref[tid * 2 + 1] = excl + v[0];
            if (tid == 255) s_pref[RB] = excl + lsum;
            e_last = e2;
            __syncthreads();
        }

        // gather this tile's 32 entries via binary search on s_pref
        if (tid < 32) {
            int row = t2 * 32 + tid;
            bool val = tid < rows;
            int rr = val ? row : 0;
            int lo = 0, hi = RB;
            while (hi - lo > 1) { int mid = (lo + hi) >> 1; if (s_pref[mid] <= rr) lo = mid; else hi = mid; }
            int sub = rr - s_pref[lo];
            s_ent[tid]  = tok_list[((size_t)e2 * RB + lo) * SLOTW + sub];
            s_gate[tid] = val ? gate_list[((size_t)e2 * RB + lo) * SLOTW + sub] : 0.0f;
        }
        __syncthreads();

        const u16* w1f = wf1 + (size_t)e2 * (128 * 512);
        const u16* w2f = wf2 + (size_t)e2 * (128 * 512);
        const u16* a0 = xbf + (size_t)(s_ent[16 * r + m] & 0xFFFF) * DM + q * 8;

        // GEMM1: k-steps in pairs, double-buffered
        short8 ab[2][2];
        short8 bb[2][2][4];
#pragma unroll
        for (int kk = 0; kk < 2; ++kk) {
            ab[0][kk] = *(const short8*)(a0 + 32 * kk);
            const u16* bp = w1f + (size_t)kk * 4096 + (size_t)(4 * c) * 512 + lane * 8;
#pragma unroll
            for (int n = 0; n < 4; ++n) bb[0][kk][n] = *(const short8*)(bp + n * 512);
        }
        f32x4 acc[4];
#pragma unroll
        for (int n = 0; n < 4; ++n) acc[n] = (f32x4){0.f, 0.f, 0.f, 0.f};

#pragma unroll
        for (int kp = 0; kp < 8; ++kp) {
            int cur = kp & 1, nxt = cur ^ 1;
            if (kp < 7) {
                int ks0 = 2 * (kp + 1);
#pragma unroll
                for (int kk = 0; kk < 2; ++kk) {
                    ab[nxt][kk] = *(const short8*)(a0 + 32 * (ks0 + kk));
                    const u16* bp = w1f + (size_t)(ks0 + kk) * 4096 + (size_t)(4 * c) * 512 + lane * 8;
#pragma unroll
                    for (int n = 0; n < 4; ++n) bb[nxt][kk][n] = *(const short8*)(bp + n * 512);
                }
            }
#pragma unroll
            for (int kk = 0; kk < 2; ++kk)
#pragma unroll
                for (int n = 0; n < 4; ++n)
                    acc[n] = __builtin_amdgcn_mfma_f32_16x16x32_bf16(ab[cur][kk],
                                                                     bb[cur][kk][n],
                                                                     acc[n], 0, 0, 0);
        }

        // relu * gate -> Hm
        {
            int rb = 16 * r + q * 4;
#pragma unroll
            for (int n = 0; n < 4; ++n)
#pragma unroll
                for (int rr2 = 0; rr2 < 4; ++rr2)
                    Hm[rb + rr2][64 * c + 16 * n + m] =
                        f2bf(fmaxf(acc[n][rr2], 0.f) * s_gate[rb + rr2]);
        }

        // GEMM2: wave owns cols [128*wv, +128); w2 frags double-buffered per k-slice
        short8 cb[2][8];
        {
            const u16* bp = w2f + (size_t)(wv * 8) * 512 + lane * 8;
#pragma unroll
            for (int n = 0; n < 8; ++n) cb[0][n] = *(const short8*)(bp + n * 512);
        }
        __syncthreads();                            // Hm ready

        f32x4 acc2[2][8];
#pragma unroll
        for (int i = 0; i < 2; ++i)
#pragma unroll
            for (int n = 0; n < 8; ++n) acc2[i][n] = (f32x4){0.f, 0.f, 0.f, 0.f};
#pragma unroll
        for (int ks = 0; ks < 4; ++ks) {
            int cur = ks & 1, nxt = cur ^ 1;
            if (ks < 3) {
                const u16* bp = w2f + (size_t)((ks + 1) * 32 + wv * 8) * 512 + lane * 8;
#pragma unroll
                for (int n = 0; n < 8; ++n) cb[nxt][n] = *(const short8*)(bp + n * 512);
            }
            short8 h0 = *(const short8*)&Hm[m][32 * ks + q * 8];
            short8 h1 = *(const short8*)&Hm[16 + m][32 * ks + q * 8];
#pragma unroll
            for (int n = 0; n < 8; ++n) {
                acc2[0][n] = __builtin_amdgcn_mfma_f32_16x16x32_bf16(h0, cb[cur][n], acc2[0][n], 0, 0, 0);
                acc2[1][n] = __builtin_amdgcn_mfma_f32_16x16x32_bf16(h1, cb[cur][n], acc2[1][n], 0, 0, 0);
            }
        }

        // epilogue: 2 passes through half-height Ct (16 rows x 512 cols)
#pragma unroll
        for (int i = 0; i < 2; ++i) {
            if (i) __syncthreads();                 // pass-0 readers done before rewrite
            {
                int rb = q * 4;
#pragma unroll
                for (int n = 0; n < 8; ++n)
#pragma unroll
                    for (int rr2 = 0; rr2 < 4; ++rr2)
                        Ct[rb + rr2][128 * wv + 16 * n + m] = f2bf(acc2[i][n][rr2]);
            }
            __syncthreads();                        // Ct pass complete
#pragma unroll
            for (int rep = 0; rep < 4; ++rep) {
                int rl = rep * 4 + wv;              // 0..15
                int rt = 16 * i + rl;               // tile row 0..31
                u16x8 v = *(const u16x8*)&Ct[rl][lane * 8];
                if (rt < rows) {
                    int en = s_ent[rt];
                    int tk = en & 0xFFFF, sl2 = en >> 16;
                    if (use_part) {
                        *(u16x8*)(part + ((size_t)tk * TK + sl2) * DM + lane * 8) = v;
                    } else {
                        float* op = out + (size_t)tk * DM + lane * 8;
#pragma unroll
                        for (int j = 0; j < 8; ++j) atomicAdd(&op[j], bf2f(v[j]));
                    }
                }
            }
        }
        __syncthreads();                            // drains all part stores (vmcnt)

        if (use_part) {
            // completion counters: exactly 4 increments per token; old==3 wins.
            // ACQ_REL after __syncthreads = the visibility pattern proven in R2/R5.
            if (tid < 32) {
                int w = 0;
                if (tid < rows) {
                    int tk = s_ent[tid] & 0xFFFF;
                    u32 old = __hip_atomic_fetch_add(&done[tk], 1u, __ATOMIC_ACQ_REL,
                                                     __HIP_MEMORY_SCOPE_AGENT);
                    if (old == 3u) w = tk + 1;
                }
                s_win[tid] = w;
            }
            __syncthreads();
            // combine won tokens: one wave per token, fully coalesced
            for (int ws2 = wv; ws2 < 32; ws2 += 4) {
                int tw = s_win[ws2];
                if (!tw) continue;
                int t = tw - 1;
                const u16* pp = part + (size_t)t * (TK * DM) + lane * 8;
                float s[8] = {0, 0, 0, 0, 0, 0, 0, 0};
#pragma unroll
                for (int k = 0; k < TK; ++k) {
                    u16x8 p = *(const u16x8*)(pp + (size_t)k * DM);
#pragma unroll
                    for (int j = 0; j < 8; ++j) s[j] += bf2f(p[j]);
                }
                float* op = out + (size_t)t * DM + lane * 8;
                *(f32x4*)(op)     = (f32x4){s[0], s[1], s[2], s[3]};
                *(f32x4*)(op + 4) = (f32x4){s[4], s[5], s[6], s[7]};
            }
        }
    }
}

extern "C" void kernel_launch(void* const* d_in, const int* in_sizes, int n_in,
                              void* d_out, int out_size, void* d_ws, size_t ws_size,
                              hipStream_t stream) {
    (void)in_sizes; (void)n_in; (void)out_size;
    const float* x   = (const float*)d_in[0];   // [N, D]
    const float* sel = (const float*)d_in[1];   // [E, D]
    const float* w1  = (const float*)d_in[2];   // [E, D, H]
    const float* w2  = (const float*)d_in[3];   // [E, H, D]
    float* out = (float*)d_out;                 // [N, D]

    char* ws = (char*)d_ws;
    int*   blk_cnt   = (int*)(ws);                                   // 64 KB
    u32*   done      = (u32*)(ws + (size_t)NE * RB * 4);             // 16 KB
    int*   tok_list  = (int*)(ws + (size_t)NE * RB * 4 + NTOK * 4);  // 2 MB
    float* gate_list = (float*)((char*)tok_list + (size_t)NE * RB * SLOTW * 4); // 2 MB
    u16*   xbf  = (u16*)((char*)gate_list + (size_t)NE * RB * SLOTW * 4);       // 4 MB
    u16*   wf1  = xbf + (size_t)NTOK * DM;                           // 4 MB
    u16*   wf2  = wf1 + (size_t)NE * HD * DM;                        // 4 MB
    u16*   part = wf2 + (size_t)NE * HD * DM;                        // 16.8 MB [t][k][c]

    size_t need = (size_t)NE * RB * 4 + NTOK * 4 + 2 * (size_t)NE * RB * SLOTW * 4
                + (size_t)NTOK * DM * 2 + 2 * (size_t)NE * HD * DM * 2
                + (size_t)NTOK * TK * DM * 2;
    int use_part = (ws_size >= need) ? 1 : 0;

    if (!use_part)
        hipMemsetAsync(d_out, 0, (size_t)NTOK * DM * sizeof(float), stream);

    // blocks [0,512) router (8 tok/block, zeroes done[]); [512,1536) swizzle.
    prep_kernel<<<1536, 256, 0, stream>>>(x, sel, w1, w2, blk_cnt, done, tok_list,
                                          gate_list, xbf, wf1, wf2);
    // 8 XCD groups x 128 blocks; tile loop + completion-counter fused combine
    moe_mlp_kernel<<<1024, 256, 0, stream>>>(xbf, wf1, wf2, blk_cnt, tok_list,
                                             gate_list, done, part, out, use_part);
}

// Round 7
// 126.275 us; speedup vs baseline: 1.6301x; 1.1200x over previous
//
#include <hip/hip_runtime.h>
#include <hip/hip_bf16.h>

// Problem constants: N tokens, D d_model, E experts, H hidden, K top-k
#define NTOK 4096
#define DM   512
#define NE   32
#define HD   128
#define TK   4
#define RB   512    // router blocks (8 tokens each)
#define SLOTW 32    // tok_list slots per (expert, router-block): 8 tok * K=4

typedef unsigned short u16;
typedef unsigned int   u32;
typedef u16   u16x4 __attribute__((ext_vector_type(4)));
typedef u16   u16x8 __attribute__((ext_vector_type(8)));
typedef short short8 __attribute__((ext_vector_type(8)));
typedef float f32x4 __attribute__((ext_vector_type(4)));
typedef int   int2v __attribute__((ext_vector_type(2)));

__device__ __forceinline__ u16 f2bf(float f) {
    union { float f; u32 u; } v; v.f = f;
    return (u16)((v.u + 0x7FFFu + ((v.u >> 16) & 1u)) >> 16);   // RNE
}
__device__ __forceinline__ float bf2f(u16 h) {
    union { u32 u; float f; } v; v.u = ((u32)h) << 16; return v.f;
}

// ---------------- fused prep ----------------
// blocks [0,512):      router, 8 tokens/block (verified R5/R6 fp64 math);
//                      deterministic per-(block,expert) slots, no atomics, no memset.
// blocks [512,1536):   weight swizzle fp32 -> bf16 fragment-major (verbatim).
__global__ __launch_bounds__(256) void prep_kernel(const float* __restrict__ x,
                                                   const float* __restrict__ sel,
                                                   const float* __restrict__ w1,
                                                   const float* __restrict__ w2,
                                                   int* __restrict__ blk_cnt,
                                                   int* __restrict__ tok_list,
                                                   float* __restrict__ gate_list,
                                                   u16* __restrict__ xbf,
                                                   u16* __restrict__ wf1,
                                                   u16* __restrict__ wf2) {
    __shared__ __align__(16) float  xs[8][520];     // 16.6 KB
    __shared__ double sc[8][33];                    // 2.1 KB
    __shared__ int    pk_e[32];
    __shared__ float  pk_g[32];
    int tid = threadIdx.x;
    int wv = tid >> 6, lane = tid & 63;

    if (blockIdx.x >= RB) {
        // ---- weight swizzle: 2 fragments per wave ----
        int m = lane & 15, q = lane >> 4;
        int f0 = ((blockIdx.x - RB) * 4 + wv) * 2;
        const float* in[2]; u16* outp[2]; int Nd[2];
#pragma unroll
        for (int u = 0; u < 2; ++u) {
            int w = f0 + u;
            if (w < 4096) {
                int e = w >> 7, rem = w & 127, ks = rem >> 3, nt = rem & 7;
                in[u] = w1 + (size_t)e * DM * HD + (size_t)(32 * ks + q * 8) * HD + 16 * nt + m;
                Nd[u] = HD;
                outp[u] = wf1 + (size_t)w * 512 + lane * 8;
            } else {
                int wl = w - 4096, e = wl >> 7, rem = wl & 127, ks = rem >> 5, nt = rem & 31;
                in[u] = w2 + (size_t)e * HD * DM + (size_t)(32 * ks + q * 8) * DM + 16 * nt + m;
                Nd[u] = DM;
                outp[u] = wf2 + (size_t)wl * 512 + lane * 8;
            }
        }
        float v[2][8];
#pragma unroll
        for (int u = 0; u < 2; ++u)
#pragma unroll
            for (int j = 0; j < 8; ++j) v[u][j] = in[u][(size_t)j * Nd[u]];
#pragma unroll
        for (int u = 0; u < 2; ++u) {
            u16x8 h;
#pragma unroll
            for (int j = 0; j < 8; ++j) h[j] = f2bf(v[u][j]);
            *(u16x8*)outp[u] = h;
        }
        return;
    }

    // ---- router: 8 tokens/block ----
    int bl = blockIdx.x;
    int tb = bl * 8;
#pragma unroll
    for (int rep = 0; rep < 4; ++rep) {
        int idx = (rep * 256 + tid) * 4;            // element in 8x512 tile
        int row = idx >> 9, col = idx & 511;
        f32x4 v = *(const f32x4*)(x + (size_t)(tb + row) * DM + col);
        *(f32x4*)&xs[row][col] = v;
        u16x4 h;
#pragma unroll
        for (int j = 0; j < 4; ++j) h[j] = f2bf(v[j]);
        *(u16x4*)(xbf + (size_t)(tb + row) * DM + col) = h;
    }
    __syncthreads();

    // thread: tok = tid&7, e = tid>>3; full 512-long fp64 dot, 4 chains,
    // combined (pa+pb)+(pc+pd) — summation order identical to verified router.
    {
        int tok = tid & 7, e = tid >> 3;
        const float* sp = sel + (size_t)e * DM;
        const float* xp = xs[tok];
        double pa = 0.0, pb = 0.0, pc = 0.0, pd = 0.0;
#pragma unroll 4
        for (int j = 0; j < 512; j += 16) {
            f32x4 x0 = *(const f32x4*)(xp + j);
            f32x4 x1 = *(const f32x4*)(xp + j + 4);
            f32x4 x2 = *(const f32x4*)(xp + j + 8);
            f32x4 x3 = *(const f32x4*)(xp + j + 12);
            f32x4 s0 = *(const f32x4*)(sp + j);
            f32x4 s1 = *(const f32x4*)(sp + j + 4);
            f32x4 s2 = *(const f32x4*)(sp + j + 8);
            f32x4 s3 = *(const f32x4*)(sp + j + 12);
#pragma unroll
            for (int k = 0; k < 4; ++k) {
                pa = fma((double)x0[k], (double)s0[k], pa);
                pb = fma((double)x1[k], (double)s1[k], pb);
                pc = fma((double)x2[k], (double)s2[k], pc);
                pd = fma((double)x3[k], (double)s3[k], pd);
            }
        }
        sc[tok][e] = (pa + pb) + (pc + pd);
    }
    __syncthreads();

    // top-k per token -> LDS pick lists
    if (tid < 8) {
        unsigned mask = 0;
        for (int k = 0; k < TK; ++k) {
            double best = -1e300; int be = 0;
            for (int ee = 0; ee < NE; ++ee) {
                double v = sc[tid][ee];
                if (!((mask >> ee) & 1u) && v > best) { best = v; be = ee; }
            }
            mask |= 1u << be;
            pk_e[tid * 4 + k] = be;
            pk_g[tid * 4 + k] = 1.0f / (1.0f + __expf(-(float)best));
        }
    }
    __syncthreads();

    // deterministic append: expert tid owns tok_list[(tid*RB+bl)*SLOTW ..]
    if (tid < NE) {
        int e2 = tid, cnt = 0;
        int base = (e2 * RB + bl) * SLOTW;
#pragma unroll
        for (int i = 0; i < 32; ++i) {
            if (pk_e[i] == e2) {
                tok_list[base + cnt]  = ((i & 3) << 16) | (tb + (i >> 2));
                gate_list[base + cnt] = pk_g[i];
                ++cnt;
            }
        }
        blk_cnt[e2 * RB + bl] = cnt;                // written for EVERY (e,bl)
    }
}

// ---------------- fused expert MLP ----------------
// Grid 1024 (8 XCD groups x 128), internal tile loop. 28.2 KB LDS (half-height Ct,
// 2-pass epilogue) + __launch_bounds__(256,4) -> 4 blocks/CU so L2-load latency in
// the GEMM loops is covered by 2x the waves vs R4. No atomics, no acquire ops in
// the loop (R6 lesson: acquire invalidates L1 and kills weight reuse).
__global__ __launch_bounds__(256, 4) void moe_mlp_kernel(const u16* __restrict__ xbf,
                                                         const u16* __restrict__ wf1,
                                                         const u16* __restrict__ wf2,
                                                         const int* __restrict__ blk_cnt,
                                                         const int* __restrict__ tok_list,
                                                         const float* __restrict__ gate_list,
                                                         u16* __restrict__ part,
                                                         float* __restrict__ out,
                                                         int use_part) {
    __shared__ int   s_tot[4];
    __shared__ int   s_red[4][4];                   // [wave][slot]
    __shared__ int   s_pref[RB + 1];                // 2.1 KB
    __shared__ int   s_ent[32];
    __shared__ float s_gate[32];
    __shared__ __align__(16) u16 Hm[32][136];       // 8.7 KB
    __shared__ __align__(16) u16 Ct[16][520];       // 16.6 KB (half-height, 2 passes)

    int tid = threadIdx.x;
    int wv = tid >> 6, lane = tid & 63;
    int xcd = blockIdx.x & 7, idx0 = blockIdx.x >> 3;   // 128 blocks per group

    // ---- per-expert totals for this group's 4 experts ----
#pragma unroll
    for (int j = 0; j < 4; ++j) {
        int2v v = *(const int2v*)&blk_cnt[(size_t)(xcd + 8 * j) * RB + tid * 2];
        int s = v[0] + v[1];
#pragma unroll
        for (int off = 32; off >= 1; off >>= 1) s += __shfl_down(s, off);
        if (lane == 0) s_red[wv][j] = s;
    }
    __syncthreads();
    if (tid < 4) s_tot[tid] = s_red[0][tid] + s_red[1][tid] + s_red[2][tid] + s_red[3][tid];
    __syncthreads();

    int c0 = s_tot[0], c1 = s_tot[1], c2 = s_tot[2], c3 = s_tot[3];
    int n0 = (c0 + 31) >> 5, n1 = (c1 + 31) >> 5, n2 = (c2 + 31) >> 5, n3 = (c3 + 31) >> 5;
    int tot = n0 + n1 + n2 + n3;

    int m = lane & 15, q = lane >> 4;
    int r = wv >> 1, c = wv & 1;                    // GEMM1: rows 16r..+16, cols 64c..+64
    int e_last = -1;

    for (int idx = idx0; idx < tot; idx += 128) {
        int e2, t2, cc;
        if (idx < n0)                { e2 = xcd;      t2 = idx;                cc = c0; }
        else if (idx < n0 + n1)      { e2 = xcd + 8;  t2 = idx - n0;           cc = c1; }
        else if (idx < n0 + n1 + n2) { e2 = xcd + 16; t2 = idx - n0 - n1;      cc = c2; }
        else                         { e2 = xcd + 24; t2 = idx - n0 - n1 - n2; cc = c3; }
        int rows = cc - t2 * 32; if (rows > 32) rows = 32;

        __syncthreads();                            // prev iter's readers done

        if (e2 != e_last) {
            // exclusive prefix scan of blk_cnt[e2][0..RB) into s_pref
            int2v v = *(const int2v*)&blk_cnt[(size_t)e2 * RB + tid * 2];
            int lsum = v[0] + v[1];
            int incl = lsum;
#pragma unroll
            for (int off = 1; off < 64; off <<= 1) {
                int t3 = __shfl_up(incl, off);
                if (lane >= off) incl += t3;
            }
            if (lane == 63) s_red[0][wv] = incl;
            __syncthreads();
            int woff = 0;
#pragma unroll
            for (int w2 = 0; w2 < 4; ++w2) if (w2 < wv) woff += s_red[0][w2];
            int excl = woff + incl - lsum;
            s_pref[tid * 2 + 0] = excl;
            s_pref[tid * 2 + 1] = excl + v[0];
            if (tid == 255) s_pref[RB] = excl + lsum;
            e_last = e2;
            __syncthreads();
        }

        // gather this tile's 32 entries via binary search on s_pref
        if (tid < 32) {
            int row = t2 * 32 + tid;
            bool val = tid < rows;
            int rr = val ? row : 0;
            int lo = 0, hi = RB;
            while (hi - lo > 1) { int mid = (lo + hi) >> 1; if (s_pref[mid] <= rr) lo = mid; else hi = mid; }
            int sub = rr - s_pref[lo];
            s_ent[tid]  = tok_list[((size_t)e2 * RB + lo) * SLOTW + sub];
            s_gate[tid] = val ? gate_list[((size_t)e2 * RB + lo) * SLOTW + sub] : 0.0f;
        }
        __syncthreads();

        const u16* w1f = wf1 + (size_t)e2 * (128 * 512);
        const u16* w2f = wf2 + (size_t)e2 * (128 * 512);
        const u16* a0 = xbf + (size_t)(s_ent[16 * r + m] & 0xFFFF) * DM + q * 8;

        // GEMM1: k-steps in pairs, double-buffered
        short8 ab[2][2];
        short8 bb[2][2][4];
#pragma unroll
        for (int kk = 0; kk < 2; ++kk) {
            ab[0][kk] = *(const short8*)(a0 + 32 * kk);
            const u16* bp = w1f + (size_t)kk * 4096 + (size_t)(4 * c) * 512 + lane * 8;
#pragma unroll
            for (int n = 0; n < 4; ++n) bb[0][kk][n] = *(const short8*)(bp + n * 512);
        }
        f32x4 acc[4];
#pragma unroll
        for (int n = 0; n < 4; ++n) acc[n] = (f32x4){0.f, 0.f, 0.f, 0.f};

#pragma unroll
        for (int kp = 0; kp < 8; ++kp) {
            int cur = kp & 1, nxt = cur ^ 1;
            if (kp < 7) {
                int ks0 = 2 * (kp + 1);
#pragma unroll
                for (int kk = 0; kk < 2; ++kk) {
                    ab[nxt][kk] = *(const short8*)(a0 + 32 * (ks0 + kk));
                    const u16* bp = w1f + (size_t)(ks0 + kk) * 4096 + (size_t)(4 * c) * 512 + lane * 8;
#pragma unroll
                    for (int n = 0; n < 4; ++n) bb[nxt][kk][n] = *(const short8*)(bp + n * 512);
                }
            }
#pragma unroll
            for (int kk = 0; kk < 2; ++kk)
#pragma unroll
                for (int n = 0; n < 4; ++n)
                    acc[n] = __builtin_amdgcn_mfma_f32_16x16x32_bf16(ab[cur][kk],
                                                                     bb[cur][kk][n],
                                                                     acc[n], 0, 0, 0);
        }

        // relu * gate -> Hm
        {
            int rb = 16 * r + q * 4;
#pragma unroll
            for (int n = 0; n < 4; ++n)
#pragma unroll
                for (int rr2 = 0; rr2 < 4; ++rr2)
                    Hm[rb + rr2][64 * c + 16 * n + m] =
                        f2bf(fmaxf(acc[n][rr2], 0.f) * s_gate[rb + rr2]);
        }

        // GEMM2: wave owns cols [128*wv, +128); w2 frags double-buffered per k-slice
        short8 cb[2][8];
        {
            const u16* bp = w2f + (size_t)(wv * 8) * 512 + lane * 8;
#pragma unroll
            for (int n = 0; n < 8; ++n) cb[0][n] = *(const short8*)(bp + n * 512);
        }
        __syncthreads();                            // Hm ready

        f32x4 acc2[2][8];
#pragma unroll
        for (int i = 0; i < 2; ++i)
#pragma unroll
            for (int n = 0; n < 8; ++n) acc2[i][n] = (f32x4){0.f, 0.f, 0.f, 0.f};
#pragma unroll
        for (int ks = 0; ks < 4; ++ks) {
            int cur = ks & 1, nxt = cur ^ 1;
            if (ks < 3) {
                const u16* bp = w2f + (size_t)((ks + 1) * 32 + wv * 8) * 512 + lane * 8;
#pragma unroll
                for (int n = 0; n < 8; ++n) cb[nxt][n] = *(const short8*)(bp + n * 512);
            }
            short8 h0 = *(const short8*)&Hm[m][32 * ks + q * 8];
            short8 h1 = *(const short8*)&Hm[16 + m][32 * ks + q * 8];
#pragma unroll
            for (int n = 0; n < 8; ++n) {
                acc2[0][n] = __builtin_amdgcn_mfma_f32_16x16x32_bf16(h0, cb[cur][n], acc2[0][n], 0, 0, 0);
                acc2[1][n] = __builtin_amdgcn_mfma_f32_16x16x32_bf16(h1, cb[cur][n], acc2[1][n], 0, 0, 0);
            }
        }

        // epilogue: 2 passes through half-height Ct (16 rows x 512 cols)
#pragma unroll
        for (int i = 0; i < 2; ++i) {
            if (i) __syncthreads();                 // pass-0 readers done before rewrite
            {
                int rb = q * 4;
#pragma unroll
                for (int n = 0; n < 8; ++n)
#pragma unroll
                    for (int rr2 = 0; rr2 < 4; ++rr2)
                        Ct[rb + rr2][128 * wv + 16 * n + m] = f2bf(acc2[i][n][rr2]);
            }
            __syncthreads();                        // Ct pass complete
#pragma unroll
            for (int rep = 0; rep < 4; ++rep) {
                int rl = rep * 4 + wv;              // 0..15
                int rt = 16 * i + rl;               // tile row 0..31
                u16x8 v = *(const u16x8*)&Ct[rl][lane * 8];
                if (rt < rows) {
                    int en = s_ent[rt];
                    int tk = en & 0xFFFF, sl2 = en >> 16;
                    if (use_part) {
                        *(u16x8*)(part + ((size_t)tk * TK + sl2) * DM + lane * 8) = v;
                    } else {
                        float* op = out + (size_t)tk * DM + lane * 8;
#pragma unroll
                        for (int j = 0; j < 8; ++j) atomicAdd(&op[j], bf2f(v[j]));
                    }
                }
            }
        }
    }
}

// ---------------- combine: out[t][c] = sum_k part[t][k][c] ----------------
// part layout [t][k][c]: per token the 4 contributions are contiguous rows ->
// reads and writes both fully coalesced.
__global__ __launch_bounds__(256) void combine_kernel(const u16* __restrict__ part,
                                                      float* __restrict__ out) {
    int g = blockIdx.x * 256 + threadIdx.x;         // 8-float chunk index
    int t = g >> 6, c8 = (g & 63) << 3;
    const u16* pp = part + (size_t)t * (TK * DM) + c8;
    float s[8] = {0, 0, 0, 0, 0, 0, 0, 0};
#pragma unroll
    for (int k = 0; k < TK; ++k) {
        u16x8 p = *(const u16x8*)(pp + (size_t)k * DM);
#pragma unroll
        for (int j = 0; j < 8; ++j) s[j] += bf2f(p[j]);
    }
    float* op = out + (size_t)t * DM + c8;
    *(f32x4*)(op)     = (f32x4){s[0], s[1], s[2], s[3]};
    *(f32x4*)(op + 4) = (f32x4){s[4], s[5], s[6], s[7]};
}

extern "C" void kernel_launch(void* const* d_in, const int* in_sizes, int n_in,
                              void* d_out, int out_size, void* d_ws, size_t ws_size,
                              hipStream_t stream) {
    (void)in_sizes; (void)n_in; (void)out_size;
    const float* x   = (const float*)d_in[0];   // [N, D]
    const float* sel = (const float*)d_in[1];   // [E, D]
    const float* w1  = (const float*)d_in[2];   // [E, D, H]
    const float* w2  = (const float*)d_in[3];   // [E, H, D]
    float* out = (float*)d_out;                 // [N, D]

    char* ws = (char*)d_ws;
    int*   blk_cnt   = (int*)(ws);                                   // 64 KB
    int*   tok_list  = (int*)(ws + (size_t)NE * RB * 4);             // 2 MB
    float* gate_list = (float*)((char*)tok_list + (size_t)NE * RB * SLOTW * 4); // 2 MB
    u16*   xbf  = (u16*)((char*)gate_list + (size_t)NE * RB * SLOTW * 4);       // 4 MB
    u16*   wf1  = xbf + (size_t)NTOK * DM;                           // 4 MB
    u16*   wf2  = wf1 + (size_t)NE * HD * DM;                        // 4 MB
    u16*   part = wf2 + (size_t)NE * HD * DM;                        // 16.8 MB [t][k][c]

    size_t need = (size_t)NE * RB * 4 + 2 * (size_t)NE * RB * SLOTW * 4
                + (size_t)NTOK * DM * 2 + 2 * (size_t)NE * HD * DM * 2
                + (size_t)NTOK * TK * DM * 2;
    int use_part = (ws_size >= need) ? 1 : 0;

    if (!use_part)
        hipMemsetAsync(d_out, 0, (size_t)NTOK * DM * sizeof(float), stream);

    // blocks [0,512) router (8 tok/block); [512,1536) swizzle. No memset nodes.
    prep_kernel<<<1536, 256, 0, stream>>>(x, sel, w1, w2, blk_cnt, tok_list,
                                          gate_list, xbf, wf1, wf2);
    // 8 XCD groups x 128 blocks; tile loop; 4 blocks/CU
    moe_mlp_kernel<<<1024, 256, 0, stream>>>(xbf, wf1, wf2, blk_cnt, tok_list,
                                             gate_list, part, out, use_part);
    if (use_part)
        combine_kernel<<<NTOK * DM / 8 / 256, 256, 0, stream>>>(part, out);
}